// Round 9
// baseline (478.408 us; speedup 1.0000x reference)
//
#include <hip/hip_runtime.h>
#include <hip/hip_bf16.h>
#include <hip/hip_cooperative_groups.h>
namespace cg = cooperative_groups;

#define N_NODES 50000
#define N_EDGES 800000
#define NB1 400       // bucketing blocks (phase 1)
#define CH  2000      // edges per bucketing block (NB1*CH == N_EDGES)
#define NBKT 196      // MSD buckets = key>>8
#define CAP 8192      // slots per bucket (mean ~4082, +64 sigma headroom)
#define GRID_ALL 512  // cooperative grid (2 blocks/CU guaranteed by launch_bounds)

typedef unsigned short ushort_t;
typedef unsigned long long u64;
typedef __attribute__((ext_vector_type(8))) short bf16x8;
typedef __attribute__((ext_vector_type(4))) float f32x4;

// ---------------- workspace layout (4-byte word offsets) ----------------
constexpr int GCUR_O  = 0;           // uint[512]: [0,196) col cursors, [256,452) row cursors
constexpr int DIS_O   = 512;         // float[50000]
constexpr int OFF_O   = 50512;       // int[50001]
constexpr int CSLOT_O = 100544;      // u64[196*8192] col buckets (w | col8 | row16)
constexpr int RSLOT_O = 3311808;     // uint[196*8192] row buckets (w24 | row8); T1S after phase 2
constexpr int RW_O    = 4917440;     // u64[800000] CSR payload (w | row)
constexpr int ABUF_O  = 6517440;     // uint[50000*96] A=[x|tx1|tx2] bf16x2
constexpr int PBUF_O  = 11317440;    // ushort[24576] packed B
constexpr int XS_O    = 11329728;    // uint[50000*32] xs = dis*x (own region; must NOT alias cslot)
constexpr int T1S_O   = RSLOT_O;     // uint[50000*32] dis*tx1 (safe: rslot dead after phase 2)

__device__ __forceinline__ ushort_t f32_to_bf16(float f) {
    unsigned u = __float_as_uint(f);
    u += 0x7fffu + ((u >> 16) & 1u);   // round-to-nearest-even
    return (ushort_t)(u >> 16);
}
__device__ __forceinline__ float bflo(unsigned u) { return __uint_as_float(u << 16); }
__device__ __forceinline__ float bfhi(unsigned u) { return __uint_as_float(u & 0xffff0000u); }
__device__ __forceinline__ unsigned packbf2(float a, float b) {
    return (unsigned)f32_to_bf16(a) | ((unsigned)f32_to_bf16(b) << 16);
}
__device__ __forceinline__ float fsigmoid(float x) { return 1.f / (1.f + __expf(-x)); }
__device__ __forceinline__ float ftanh(float x) {
    x = fminf(15.f, fmaxf(-15.f, x));
    float e = __expf(2.f * x);
    return (e - 1.f) / (e + 1.f);
}

// ---- fused pipeline: zero -> bucket/xcast/packB -> sort/deg+xs -> prop1 -> prop2 ----
__global__ __launch_bounds__(512, 4) void k_all(
    const int* __restrict__ ei, const float* __restrict__ ew,
    const float* __restrict__ x, const float* __restrict__ Wxz,
    const float* __restrict__ Wxh, unsigned* __restrict__ gcur,
    u64* __restrict__ cslot, unsigned* __restrict__ rslot,
    float* __restrict__ dis, int* __restrict__ off, u64* __restrict__ rw,
    unsigned* __restrict__ abuf, ushort_t* __restrict__ pbuf,
    unsigned* __restrict__ xs, unsigned* __restrict__ t1s) {
    cg::grid_group grid = cg::this_grid();
    const int bid = blockIdx.x, t = threadIdx.x;
    __shared__ unsigned colbuf[CH], rowbuf[CH];
    __shared__ unsigned h1[256], h2[256], b1[256], b2[256];
    __shared__ float facc[256];

    // ---- phase 0: zero the cursors (replaces the memset dispatch) ----
    if (bid == 0) gcur[t] = 0u;
    grid.sync();

    // ---- phase 1: dual MSD bucketing + x bf16 cast + packB ----
    if (bid < NB1) {
        if (t < 256) { h1[t] = 0; h2[t] = 0; }
        __syncthreads();
        int e0 = bid * CH;
        for (int i = t; i < CH; i += 512) {
            unsigned r = (unsigned)ei[e0 + i];
            unsigned c = (unsigned)ei[N_EDGES + e0 + i];
            rowbuf[i] = r;
            colbuf[i] = c;
            atomicAdd(&h1[c >> 8], 1u);
            atomicAdd(&h2[r >> 8], 1u);
        }
        __syncthreads();
        if (t < NBKT) {
            b1[t] = atomicAdd(&gcur[t], h1[t]);
            b2[t] = atomicAdd(&gcur[256 + t], h2[t]);
        }
        __syncthreads();
        if (t < 256) { h1[t] = 0; h2[t] = 0; }   // reuse as local cursors
        __syncthreads();
        for (int i = t; i < CH; i += 512) {
            unsigned c = colbuf[i];
            unsigned r = rowbuf[i];
            unsigned w = __float_as_uint(ew[e0 + i]);
            unsigned dc = c >> 8;
            unsigned pc = b1[dc] + atomicAdd(&h1[dc], 1u);
            if (pc < CAP)
                cslot[dc * CAP + pc] = ((u64)w << 32) | ((c & 255u) << 16) | (r & 0xFFFFu);
            unsigned dr = r >> 8;
            unsigned pr = b2[dr] + atomicAdd(&h2[dr], 1u);
            if (pr < CAP) rslot[dr * CAP + pr] = (w & 0xFFFFFF00u) | (r & 255u);
        }
    } else if (bid < NB1 + 98) {                 // plain-x bf16 cast into A cols [0,64)
        int n0 = (bid - NB1) * 512;
        for (int idx = t; idx < 512 * 32; idx += 512) {
            int n = n0 + (idx >> 5);
            if (n < N_NODES) {
                int q = idx & 31;
                float2 xv = ((const float2*)x)[n * 32 + q];
                abuf[n * 96 + q] = packbf2(xv.x, xv.y);
            }
        }
    } else if (bid == NB1 + 98) {                // pack B into MFMA fragment order
        for (int idx = t; idx < 24576; idx += 512) {
            int k = idx >> 7, n = idx & 127;
            float v = (n < 64) ? Wxz[k * 64 + n] : Wxh[k * 64 + (n - 64)];
            int c = n >> 4, s = k >> 5, l = (((k >> 3) & 3) << 4) | (n & 15), j = k & 7;
            pbuf[((c * 6 + s) * 64 + l) * 8 + j] = f32_to_bf16(v);
        }
    }
    grid.sync();

    // ---- phase 2: blocks [0,196) sort -> off+rw ; [196,392) deg -> dis, xs ----
    if (bid < NBKT) {
        if (t < 256) {
            b1[t] = (t < NBKT) ? gcur[t] : 0u;
            h1[t] = 0;
        }
        __syncthreads();
        for (int o = 1; o < 256; o <<= 1) {      // inclusive scan of bucket sizes
            unsigned v = (t < 256 && t >= o) ? b1[t - o] : 0u;
            __syncthreads();
            if (t < 256) b1[t] += v;
            __syncthreads();
        }
        unsigned szb = gcur[bid];
        unsigned sz = min(szb, (unsigned)CAP);
        unsigned base = b1[bid] - szb;           // exclusive prefix
        const u64* cs = cslot + (size_t)bid * CAP;
        for (unsigned i = t; i < sz; i += 512)   // pass 1: digit histogram
            atomicAdd(&h1[((unsigned)cs[i] >> 16) & 255u], 1u);
        __syncthreads();
        unsigned h0 = (t < 256) ? h1[t] : 0u;
        if (t < 256) h2[t] = h0;
        __syncthreads();
        for (int o = 1; o < 256; o <<= 1) {      // inclusive scan of digit hist
            unsigned v = (t < 256 && t >= o) ? h2[t - o] : 0u;
            __syncthreads();
            if (t < 256) h2[t] += v;
            __syncthreads();
        }
        if (t < 256) {
            h2[t] -= h0;                         // exclusive
            b2[t] = 0u;
            int c = bid * 256 + t;
            if (c <= N_NODES) off[c] = (int)(base + h2[t]);
        }
        __syncthreads();
        for (unsigned i = t; i < sz; i += 512) { // pass 2: re-read + direct scatter
            u64 v = cs[i];
            unsigned lo = (unsigned)v;
            unsigned d = (lo >> 16) & 255u;
            unsigned p = h2[d] + atomicAdd(&b2[d], 1u);
            rw[base + p] = ((v >> 32) << 32) | (lo & 0xFFFFu);
        }
    } else if (bid < 2 * NBKT) {
        int b = bid - NBKT;
        if (t < 256) facc[t] = 0.f;
        __syncthreads();
        unsigned szr = min(gcur[256 + b], (unsigned)CAP);
        const unsigned* rs = rslot + (size_t)b * CAP;
        for (unsigned i = t; i < szr; i += 512)
            atomicAdd(&facc[rs[i] & 255u], __uint_as_float(rs[i] & 0xFFFFFF00u));
        __syncthreads();
        if (t < 256) {
            float d = facc[t];
            float r = d > 0.f ? rsqrtf(d) : 0.f;
            facc[t] = r;
            int n = b * 256 + t;
            if (n < N_NODES) dis[n] = r;
        }
        __syncthreads();
        for (int idx = t; idx < 8192; idx += 512) {
            int nl = idx >> 5, q = idx & 31;
            int n = b * 256 + nl;
            if (n < N_NODES) {
                float2 xv = ((const float2*)x)[n * 32 + q];
                float r = facc[nl];
                xs[n * 32 + q] = packbf2(r * xv.x, r * xv.y);
            }
        }
    }
    grid.sync();

    // ---- phase 3: prop1 — half-wave per node, grid-stride ----
    {
        int hw = (bid * 512 + t) >> 5, q = t & 31;
        for (int node = hw; node < N_NODES; node += GRID_ALL * 16) {
            int b = off[node], end = off[node + 1];
            float di = dis[node];
            float a0 = 0.f, a1 = 0.f;
            for (; b + 3 < end; b += 4) {
                u64 v0 = rw[b], v1 = rw[b + 1], v2 = rw[b + 2], v3 = rw[b + 3];
                unsigned u0 = xs[((unsigned)v0 & 0xFFFFu) * 32 + q];
                unsigned u1 = xs[((unsigned)v1 & 0xFFFFu) * 32 + q];
                unsigned u2 = xs[((unsigned)v2 & 0xFFFFu) * 32 + q];
                unsigned u3 = xs[((unsigned)v3 & 0xFFFFu) * 32 + q];
                float w0 = __uint_as_float((unsigned)(v0 >> 32));
                float w1 = __uint_as_float((unsigned)(v1 >> 32));
                float w2 = __uint_as_float((unsigned)(v2 >> 32));
                float w3 = __uint_as_float((unsigned)(v3 >> 32));
                a0 += w0 * bflo(u0) + w1 * bflo(u1) + w2 * bflo(u2) + w3 * bflo(u3);
                a1 += w0 * bfhi(u0) + w1 * bfhi(u1) + w2 * bfhi(u2) + w3 * bfhi(u3);
            }
            for (; b < end; ++b) {
                u64 v = rw[b];
                unsigned u = xs[((unsigned)v & 0xFFFFu) * 32 + q];
                float w = __uint_as_float((unsigned)(v >> 32));
                a0 += w * bflo(u);
                a1 += w * bfhi(u);
            }
            float t0 = -di * a0, t1v = -di * a1;
            abuf[node * 96 + 32 + q] = packbf2(t0, t1v);
            t1s[node * 32 + q] = packbf2(di * t0, di * t1v);
        }
    }
    grid.sync();

    // ---- phase 4: prop2 ----
    {
        int hw = (bid * 512 + t) >> 5, q = t & 31;
        for (int node = hw; node < N_NODES; node += GRID_ALL * 16) {
            int b = off[node], end = off[node + 1];
            float di = dis[node];
            float a0 = 0.f, a1 = 0.f;
            for (; b + 3 < end; b += 4) {
                u64 v0 = rw[b], v1 = rw[b + 1], v2 = rw[b + 2], v3 = rw[b + 3];
                unsigned u0 = t1s[((unsigned)v0 & 0xFFFFu) * 32 + q];
                unsigned u1 = t1s[((unsigned)v1 & 0xFFFFu) * 32 + q];
                unsigned u2 = t1s[((unsigned)v2 & 0xFFFFu) * 32 + q];
                unsigned u3 = t1s[((unsigned)v3 & 0xFFFFu) * 32 + q];
                float w0 = __uint_as_float((unsigned)(v0 >> 32));
                float w1 = __uint_as_float((unsigned)(v1 >> 32));
                float w2 = __uint_as_float((unsigned)(v2 >> 32));
                float w3 = __uint_as_float((unsigned)(v3 >> 32));
                a0 += w0 * bflo(u0) + w1 * bflo(u1) + w2 * bflo(u2) + w3 * bflo(u3);
                a1 += w0 * bfhi(u0) + w1 * bfhi(u1) + w2 * bfhi(u2) + w3 * bfhi(u3);
            }
            for (; b < end; ++b) {
                u64 v = rw[b];
                unsigned u = t1s[((unsigned)v & 0xFFFFu) * 32 + q];
                float w = __uint_as_float((unsigned)(v >> 32));
                a0 += w * bflo(u);
                a1 += w * bfhi(u);
            }
            float2 xv = ((const float2*)x)[node * 32 + q];
            abuf[node * 96 + 64 + q] = packbf2(-2.f * di * a0 - xv.x,
                                               -2.f * di * a1 - xv.y);
        }
    }
}

// ---- MFMA GEMM [50000x192]@[192x128] + GRU combine + head ----
__global__ __launch_bounds__(256) void k_gemm(
    const ushort_t* __restrict__ ab, const ushort_t* __restrict__ pbuf,
    const float* __restrict__ bxz, const float* __restrict__ bhz,
    const float* __restrict__ bxh, const float* __restrict__ bhh,
    const float* __restrict__ Wlin, const float* __restrict__ blin,
    float2* __restrict__ out) {
    __shared__ ushort_t bsh[24576];
    int tid = threadIdx.x;
    {
        uint4* s4 = (uint4*)bsh;
        const uint4* g4 = (const uint4*)pbuf;
        for (int i = tid; i < 3072; i += 256) s4[i] = g4[i];
    }
    __syncthreads();

    int wave = tid >> 6, lane = tid & 63;
    int quad = lane >> 4, m = lane & 15;
    int arow = blockIdx.x * 64 + wave * 16 + m;
    const ushort_t* ap = ab + (size_t)arow * 192 + quad * 8;

    f32x4 acc[8];
#pragma unroll
    for (int c = 0; c < 8; ++c) acc[c] = (f32x4){0.f, 0.f, 0.f, 0.f};
#pragma unroll
    for (int s = 0; s < 6; ++s) {
        bf16x8 af = *(const bf16x8*)(ap + s * 32);
#pragma unroll
        for (int c = 0; c < 8; ++c) {
            bf16x8 bfr = *(const bf16x8*)(bsh + ((c * 6 + s) * 64 + lane) * 8);
            acc[c] = __builtin_amdgcn_mfma_f32_16x16x32_bf16(af, bfr, acc[c], 0, 0, 0);
        }
    }
    float bzv[4], bhv[4], wl0[4], wl1[4];
#pragma unroll
    for (int c = 0; c < 4; ++c) {
        int col = c * 16 + m;
        bzv[c] = bxz[col] + bhz[col];
        bhv[c] = bxh[col] + bhh[col];
        wl0[c] = Wlin[2 * col];
        wl1[c] = Wlin[2 * col + 1];
    }
    float bl0 = blin[0], bl1 = blin[1];
#pragma unroll
    for (int i = 0; i < 4; ++i) {
        float p0 = 0.f, p1 = 0.f;
#pragma unroll
        for (int c = 0; c < 4; ++c) {
            float z  = fsigmoid(acc[c][i] + bzv[c]);
            float ht = ftanh(acc[c + 4][i] + bhv[c]);
            float t  = ftanh((1.f - z) * ht);
            p0 += t * wl0[c];
            p1 += t * wl1[c];
        }
        for (int o = 1; o <= 8; o <<= 1) {
            p0 += __shfl_xor(p0, o, 64);
            p1 += __shfl_xor(p1, o, 64);
        }
        int g = blockIdx.x * 64 + wave * 16 + quad * 4 + i;
        if (m == 0 && g < N_NODES)
            out[g] = make_float2(fsigmoid(p0 + bl0), fsigmoid(p1 + bl1));
    }
}

extern "C" void kernel_launch(void* const* d_in, const int* in_sizes, int n_in,
                              void* d_out, int out_size, void* d_ws, size_t ws_size,
                              hipStream_t stream) {
    const int*   ei   = (const int*)d_in[1];
    const float* ew   = (const float*)d_in[2];
    const float* x    = (const float*)d_in[0];
    const float* Wxz  = (const float*)d_in[3];
    const float* bxz  = (const float*)d_in[4];
    const float* bhz  = (const float*)d_in[6];
    const float* Wxh  = (const float*)d_in[11];
    const float* bxh  = (const float*)d_in[12];
    const float* bhh  = (const float*)d_in[14];
    const float* Wlin = (const float*)d_in[15];
    const float* blin = (const float*)d_in[16];

    float*    ws    = (float*)d_ws;
    unsigned* gcur  = (unsigned*)(ws + GCUR_O);
    float*    dis   = ws + DIS_O;
    int*      off   = (int*)(ws + OFF_O);
    u64*      cslot = (u64*)(ws + CSLOT_O);
    unsigned* rslot = (unsigned*)(ws + RSLOT_O);
    u64*      rw    = (u64*)(ws + RW_O);
    unsigned* abuf  = (unsigned*)(ws + ABUF_O);
    ushort_t* pbuf  = (ushort_t*)(ws + PBUF_O);
    unsigned* xs    = (unsigned*)(ws + XS_O);
    unsigned* t1s   = (unsigned*)(ws + T1S_O);

    void* args[] = {(void*)&ei, (void*)&ew, (void*)&x, (void*)&Wxz, (void*)&Wxh,
                    (void*)&gcur, (void*)&cslot, (void*)&rslot, (void*)&dis,
                    (void*)&off, (void*)&rw, (void*)&abuf, (void*)&pbuf,
                    (void*)&xs, (void*)&t1s};
    hipLaunchCooperativeKernel((const void*)k_all, dim3(GRID_ALL), dim3(512),
                               args, 0, stream);
    k_gemm<<<782, 256, 0, stream>>>((const ushort_t*)abuf, pbuf, bxz, bhz, bxh, bhh,
                                    Wlin, blin, (float2*)d_out);
}

// Round 10
// 218.121 us; speedup vs baseline: 2.1933x; 2.1933x over previous
//
#include <hip/hip_runtime.h>
#include <hip/hip_bf16.h>

#define N_NODES 50000
#define N_EDGES 800000
#define NB1 400       // k1 bucketing blocks
#define CH  2000      // edges per k1 block (NB1*CH == N_EDGES)
#define NBKT 196      // MSD buckets = key>>8
#define CAP 8192      // slots per bucket (mean ~4082, +64 sigma headroom)
#define SORT_MAX 6144 // k2 LDS sort capacity per bucket (+32 sigma)

typedef unsigned short ushort_t;
typedef unsigned long long u64;
typedef __attribute__((ext_vector_type(8))) short bf16x8;
typedef __attribute__((ext_vector_type(4))) float f32x4;

// ---------------- workspace layout (4-byte word offsets) ----------------
constexpr int GCUR_O  = 0;           // uint[512]: [0,196) col cursors, [256,452) row cursors
constexpr int DIS_O   = 512;         // float[50000]
constexpr int OFF_O   = 50512;       // int[50001]
constexpr int CSLOT_O = 100544;      // u64[196*8192] col buckets (w | dc8 | col8 | row16)
constexpr int RSLOT_O = 3311808;     // uint[196*8192] row buckets (w24 | row8); T1S after k2
constexpr int RW_O    = 4917440;     // u64[800000] CSR payload (w | row)
constexpr int ABUF_O  = 6517440;     // uint[50000*96] A=[x|tx1|tx2] bf16x2
constexpr int PBUF_O  = 11317440;    // ushort[24576] packed B
constexpr int XS_O    = 11329728;    // uint[50000*32] xs = dis*x (own region; must NOT alias cslot)
constexpr int T1S_O   = RSLOT_O;     // uint[50000*32] dis*tx1 (safe: rslot dead after k2)

__device__ __forceinline__ ushort_t f32_to_bf16(float f) {
    unsigned u = __float_as_uint(f);
    u += 0x7fffu + ((u >> 16) & 1u);   // round-to-nearest-even
    return (ushort_t)(u >> 16);
}
__device__ __forceinline__ float bflo(unsigned u) { return __uint_as_float(u << 16); }
__device__ __forceinline__ float bfhi(unsigned u) { return __uint_as_float(u & 0xffff0000u); }
__device__ __forceinline__ unsigned packbf2(float a, float b) {
    return (unsigned)f32_to_bf16(a) | ((unsigned)f32_to_bf16(b) << 16);
}
__device__ __forceinline__ float fsigmoid(float x) { return 1.f / (1.f + __expf(-x)); }
__device__ __forceinline__ float ftanh(float x) {
    x = fminf(15.f, fmaxf(-15.f, x));
    float e = __expf(2.f * x);
    return (e - 1.f) / (e + 1.f);
}

// ---- k1: dual MSD bucketing with LOCAL COUNTING SORT for coalesced writes ----
// Round-8's direct scatter issued 64 random lines per wave-store (1.6M line txns).
// Here each block sorts its 2000 edges by bucket in LDS, then streams runs out
// (mean run ~10 -> ~6x fewer line transactions).
__global__ __launch_bounds__(512, 4) void k1(
    const int* __restrict__ ei, const float* __restrict__ ew,
    const float* __restrict__ Wxz, const float* __restrict__ Wxh,
    unsigned* __restrict__ gcur, u64* __restrict__ cslot,
    unsigned* __restrict__ rslot, ushort_t* __restrict__ pbuf) {
    int bid = blockIdx.x, t = threadIdx.x;
    __shared__ u64 pC[CH];                 // staged payloads (w|dc|c8|r16)   16 KB
    __shared__ u64 sC[CH];                 // bucket-sorted col payloads      16 KB
    __shared__ unsigned sR[CH];            // bucket-sorted row payloads       8 KB
    __shared__ unsigned char dCp[CH], dRp[CH];  // bucket id per sorted pos    4 KB
    __shared__ unsigned hc[256], hr[256], scC[256], scR[256], bc[256], br[256]; // 6 KB
    if (bid < NB1) {
        if (t < 256) { hc[t] = 0; hr[t] = 0; }
        __syncthreads();
        int e0 = bid * CH;
        for (int i = t; i < CH; i += 512) {           // pass 1: stage + histograms
            unsigned r = (unsigned)ei[e0 + i];
            unsigned c = (unsigned)ei[N_EDGES + e0 + i];
            unsigned w = __float_as_uint(ew[e0 + i]);
            unsigned dc = c >> 8;
            pC[i] = ((u64)w << 32) | (dc << 24) | ((c & 255u) << 16) | (r & 0xFFFFu);
            atomicAdd(&hc[dc], 1u);
            atomicAdd(&hr[r >> 8], 1u);
        }
        __syncthreads();
        if (t < NBKT) {                                // global slot allocation
            bc[t] = atomicAdd(&gcur[t], hc[t]);
            br[t] = atomicAdd(&gcur[256 + t], hr[t]);
        }
        unsigned vC = (t < 256) ? hc[t] : 0u, vR = (t < 256) ? hr[t] : 0u;
        if (t < 256) { scC[t] = vC; scR[t] = vR; }
        __syncthreads();
        for (int o = 1; o < 256; o <<= 1) {            // inclusive scans
            unsigned aC = (t < 256 && t >= o) ? scC[t - o] : 0u;
            unsigned aR = (t < 256 && t >= o) ? scR[t - o] : 0u;
            __syncthreads();
            if (t < 256) { scC[t] += aC; scR[t] += aR; }
            __syncthreads();
        }
        if (t < 256) { scC[t] -= vC; scR[t] -= vR; hc[t] = 0; hr[t] = 0; }  // exclusive + cursors
        __syncthreads();
        for (int i = t; i < CH; i += 512) {            // pass 2: scatter into sorted LDS
            u64 p = pC[i];
            unsigned dc = (unsigned)(p >> 24) & 255u;
            unsigned pc = scC[dc] + atomicAdd(&hc[dc], 1u);
            sC[pc] = p;
            dCp[pc] = (unsigned char)dc;
            unsigned r = (unsigned)p & 0xFFFFu;
            unsigned w = (unsigned)(p >> 32);
            unsigned dr = r >> 8;
            unsigned pr = scR[dr] + atomicAdd(&hr[dr], 1u);
            sR[pr] = (w & 0xFFFFFF00u) | (r & 255u);
            dRp[pr] = (unsigned char)dr;
        }
        __syncthreads();
        for (int i = t; i < CH; i += 512) {            // pass 3: coalesced global streams
            unsigned dc = dCp[i];
            unsigned slotC = bc[dc] + (unsigned)i - scC[dc];
            if (slotC < CAP) cslot[(size_t)dc * CAP + slotC] = sC[i];
            unsigned dr = dRp[i];
            unsigned slotR = br[dr] + (unsigned)i - scR[dr];
            if (slotR < CAP) rslot[(size_t)dr * CAP + slotR] = sR[i];
        }
    } else {                                           // pack B into MFMA fragment order
        for (int idx = t; idx < 24576; idx += 512) {
            int k = idx >> 7, n = idx & 127;
            float v = (n < 64) ? Wxz[k * 64 + n] : Wxh[k * 64 + (n - 64)];
            int c = n >> 4, s = k >> 5, l = (((k >> 3) & 3) << 4) | (n & 15), j = k & 7;
            pbuf[((c * 6 + s) * 64 + l) * 8 + j] = f32_to_bf16(v);
        }
    }
}

// ---- k2: blocks [0,196): per-bucket LDS sort -> off + direct-scatter rw
//          blocks [196,392): deg (LDS fadd) -> dis, x-cast, xs = dis*x ----
__global__ __launch_bounds__(512) void k2(
    const float* __restrict__ x, const unsigned* __restrict__ gcur,
    const u64* __restrict__ cslot, const unsigned* __restrict__ rslot,
    float* __restrict__ dis, int* __restrict__ off, u64* __restrict__ rw,
    unsigned* __restrict__ abuf, unsigned* __restrict__ xs) {
    int bid = blockIdx.x, t = threadIdx.x;
    __shared__ unsigned rawA[SORT_MAX], rawB[SORT_MAX];
    __shared__ unsigned hist[256], hsc[256], cur[256], gs[256];
    __shared__ float facc[256];

    if (bid < NBKT) {
        // ---- phase A: sort col bucket bid by col&255 -> off + (row,w) CSR ----
        if (t < 256) {
            gs[t] = (t < NBKT) ? gcur[t] : 0u;
            hist[t] = 0;
        }
        __syncthreads();
        for (int o = 1; o < 256; o <<= 1) {          // inclusive scan of bucket sizes
            unsigned v = (t < 256 && t >= o) ? gs[t - o] : 0u;
            __syncthreads();
            if (t < 256) gs[t] += v;
            __syncthreads();
        }
        unsigned szb = gcur[bid];
        unsigned sz = min(szb, (unsigned)SORT_MAX);
        unsigned base = gs[bid] - szb;               // exclusive prefix
        for (unsigned i = t; i < sz; i += 512) {
            u64 v = cslot[(size_t)bid * CAP + i];
            unsigned lo = (unsigned)v;
            rawA[i] = lo;
            rawB[i] = (unsigned)(v >> 32);
            atomicAdd(&hist[(lo >> 16) & 255u], 1u);
        }
        __syncthreads();
        unsigned h0 = (t < 256) ? hist[t] : 0u;
        if (t < 256) hsc[t] = h0;
        __syncthreads();
        for (int o = 1; o < 256; o <<= 1) {          // inclusive scan of digit hist
            unsigned v = (t < 256 && t >= o) ? hsc[t - o] : 0u;
            __syncthreads();
            if (t < 256) hsc[t] += v;
            __syncthreads();
        }
        if (t < 256) {
            hsc[t] -= h0;                            // exclusive
            cur[t] = 0u;
            int c = bid * 256 + t;
            if (c <= N_NODES) off[c] = (int)(base + hsc[t]);
        }
        __syncthreads();
        for (unsigned i = t; i < sz; i += 512) {     // position + direct global scatter
            unsigned lo = rawA[i];
            unsigned d = (lo >> 16) & 255u;
            unsigned p = hsc[d] + atomicAdd(&cur[d], 1u);
            rw[base + p] = ((u64)rawB[i] << 32) | (lo & 0xFFFFu);
        }
    } else {
        // ---- phase B: deg for rows [b*256,+256), dis, x-cast + xs ----
        int b = bid - NBKT;
        if (t < 256) facc[t] = 0.f;
        __syncthreads();
        unsigned szr = min(gcur[256 + b], (unsigned)CAP);
        const unsigned* rs = rslot + (size_t)b * CAP;
        for (unsigned i = t; i < szr; i += 512)
            atomicAdd(&facc[rs[i] & 255u], __uint_as_float(rs[i] & 0xFFFFFF00u));
        __syncthreads();
        if (t < 256) {
            float d = facc[t];
            float r = d > 0.f ? rsqrtf(d) : 0.f;
            facc[t] = r;
            int n = b * 256 + t;
            if (n < N_NODES) dis[n] = r;
        }
        __syncthreads();
        for (int idx = t; idx < 8192; idx += 512) {  // x-cast + xs from one x load
            int nl = idx >> 5, q = idx & 31;
            int n = b * 256 + nl;
            if (n < N_NODES) {
                float2 xv = ((const float2*)x)[n * 32 + q];
                float r = facc[nl];
                abuf[n * 96 + q] = packbf2(xv.x, xv.y);          // plain x bf16
                xs[n * 32 + q] = packbf2(r * xv.x, r * xv.y);    // dis*x bf16
            }
        }
    }
}

// ---- prop: one wave per node; halves handle edge sub-ranges; 8 gathers in flight/half ----
// mode 0: tx1 = -dis*sum(w*xs[row]); write abuf tx1 + t1s = dis*tx1
// mode 1: tx2 = 2*(-dis*sum(w*t1s[row])) - x(fp32); write abuf tx2
__global__ __launch_bounds__(256) void k_prop(
    const int* __restrict__ off, const u64* __restrict__ rw,
    const unsigned* __restrict__ xsrc, const float* __restrict__ dis,
    const float* __restrict__ xf, unsigned* __restrict__ abuf,
    unsigned* __restrict__ t1s, int mode) {
    int node = (blockIdx.x * 256 + threadIdx.x) >> 6;
    if (node >= N_NODES) return;
    int lane = threadIdx.x & 63, h = lane >> 5, q = lane & 31;
    int b = off[node], end = off[node + 1];
    float di = dis[node];
    float acc0 = 0.f, acc1 = 0.f;
    for (; b + 15 < end; b += 16) {                  // 16 edges/iter: 8 per half in flight
        const u64* p = rw + b + h * 8;
        u64 v0 = p[0], v1 = p[1], v2 = p[2], v3 = p[3];
        u64 v4 = p[4], v5 = p[5], v6 = p[6], v7 = p[7];
        unsigned u0 = xsrc[((unsigned)v0 & 0xFFFFu) * 32 + q];
        unsigned u1 = xsrc[((unsigned)v1 & 0xFFFFu) * 32 + q];
        unsigned u2 = xsrc[((unsigned)v2 & 0xFFFFu) * 32 + q];
        unsigned u3 = xsrc[((unsigned)v3 & 0xFFFFu) * 32 + q];
        unsigned u4 = xsrc[((unsigned)v4 & 0xFFFFu) * 32 + q];
        unsigned u5 = xsrc[((unsigned)v5 & 0xFFFFu) * 32 + q];
        unsigned u6 = xsrc[((unsigned)v6 & 0xFFFFu) * 32 + q];
        unsigned u7 = xsrc[((unsigned)v7 & 0xFFFFu) * 32 + q];
        float w0 = __uint_as_float((unsigned)(v0 >> 32));
        float w1 = __uint_as_float((unsigned)(v1 >> 32));
        float w2 = __uint_as_float((unsigned)(v2 >> 32));
        float w3 = __uint_as_float((unsigned)(v3 >> 32));
        float w4 = __uint_as_float((unsigned)(v4 >> 32));
        float w5 = __uint_as_float((unsigned)(v5 >> 32));
        float w6 = __uint_as_float((unsigned)(v6 >> 32));
        float w7 = __uint_as_float((unsigned)(v7 >> 32));
        acc0 += w0 * bflo(u0) + w1 * bflo(u1) + w2 * bflo(u2) + w3 * bflo(u3)
              + w4 * bflo(u4) + w5 * bflo(u5) + w6 * bflo(u6) + w7 * bflo(u7);
        acc1 += w0 * bfhi(u0) + w1 * bfhi(u1) + w2 * bfhi(u2) + w3 * bfhi(u3)
              + w4 * bfhi(u4) + w5 * bfhi(u5) + w6 * bfhi(u6) + w7 * bfhi(u7);
    }
    for (; b + 1 < end; b += 2) {
        u64 v = rw[b + h];
        unsigned u = xsrc[((unsigned)v & 0xFFFFu) * 32 + q];
        float w = __uint_as_float((unsigned)(v >> 32));
        acc0 += w * bflo(u);
        acc1 += w * bfhi(u);
    }
    if (b < end && h == 0) {                         // odd leftover edge
        u64 v = rw[b];
        unsigned u = xsrc[((unsigned)v & 0xFFFFu) * 32 + q];
        float w = __uint_as_float((unsigned)(v >> 32));
        acc0 += w * bflo(u);
        acc1 += w * bfhi(u);
    }
    acc0 += __shfl_xor(acc0, 32, 64);
    acc1 += __shfl_xor(acc1, 32, 64);
    if (h == 0) {
        float t0 = -di * acc0, t1v = -di * acc1;
        if (mode == 0) {
            abuf[node * 96 + 32 + q] = packbf2(t0, t1v);
            t1s[node * 32 + q] = packbf2(di * t0, di * t1v);
        } else {
            float2 xv = ((const float2*)xf)[node * 32 + q];
            abuf[node * 96 + 64 + q] = packbf2(2.f * t0 - xv.x, 2.f * t1v - xv.y);
        }
    }
}

// ---- MFMA GEMM [50000x192]@[192x128] + GRU combine + head ----
__global__ __launch_bounds__(256) void k_gemm(
    const ushort_t* __restrict__ ab, const ushort_t* __restrict__ pbuf,
    const float* __restrict__ bxz, const float* __restrict__ bhz,
    const float* __restrict__ bxh, const float* __restrict__ bhh,
    const float* __restrict__ Wlin, const float* __restrict__ blin,
    float2* __restrict__ out) {
    __shared__ ushort_t bsh[24576];
    int tid = threadIdx.x;
    {
        uint4* s4 = (uint4*)bsh;
        const uint4* g4 = (const uint4*)pbuf;
        for (int i = tid; i < 3072; i += 256) s4[i] = g4[i];
    }
    __syncthreads();

    int wave = tid >> 6, lane = tid & 63;
    int quad = lane >> 4, m = lane & 15;
    int arow = blockIdx.x * 64 + wave * 16 + m;
    const ushort_t* ap = ab + (size_t)arow * 192 + quad * 8;

    f32x4 acc[8];
#pragma unroll
    for (int c = 0; c < 8; ++c) acc[c] = (f32x4){0.f, 0.f, 0.f, 0.f};
#pragma unroll
    for (int s = 0; s < 6; ++s) {
        bf16x8 af = *(const bf16x8*)(ap + s * 32);
#pragma unroll
        for (int c = 0; c < 8; ++c) {
            bf16x8 bfr = *(const bf16x8*)(bsh + ((c * 6 + s) * 64 + lane) * 8);
            acc[c] = __builtin_amdgcn_mfma_f32_16x16x32_bf16(af, bfr, acc[c], 0, 0, 0);
        }
    }
    float bzv[4], bhv[4], wl0[4], wl1[4];
#pragma unroll
    for (int c = 0; c < 4; ++c) {
        int col = c * 16 + m;
        bzv[c] = bxz[col] + bhz[col];
        bhv[c] = bxh[col] + bhh[col];
        wl0[c] = Wlin[2 * col];
        wl1[c] = Wlin[2 * col + 1];
    }
    float bl0 = blin[0], bl1 = blin[1];
#pragma unroll
    for (int i = 0; i < 4; ++i) {
        float p0 = 0.f, p1 = 0.f;
#pragma unroll
        for (int c = 0; c < 4; ++c) {
            float z  = fsigmoid(acc[c][i] + bzv[c]);
            float ht = ftanh(acc[c + 4][i] + bhv[c]);
            float t  = ftanh((1.f - z) * ht);
            p0 += t * wl0[c];
            p1 += t * wl1[c];
        }
        for (int o = 1; o <= 8; o <<= 1) {
            p0 += __shfl_xor(p0, o, 64);
            p1 += __shfl_xor(p1, o, 64);
        }
        int g = blockIdx.x * 64 + wave * 16 + quad * 4 + i;
        if (m == 0 && g < N_NODES)
            out[g] = make_float2(fsigmoid(p0 + bl0), fsigmoid(p1 + bl1));
    }
}

extern "C" void kernel_launch(void* const* d_in, const int* in_sizes, int n_in,
                              void* d_out, int out_size, void* d_ws, size_t ws_size,
                              hipStream_t stream) {
    const float* x    = (const float*)d_in[0];
    const int*   ei   = (const int*)d_in[1];
    const float* ew   = (const float*)d_in[2];
    const float* Wxz  = (const float*)d_in[3];
    const float* bxz  = (const float*)d_in[4];
    const float* bhz  = (const float*)d_in[6];
    const float* Wxh  = (const float*)d_in[11];
    const float* bxh  = (const float*)d_in[12];
    const float* bhh  = (const float*)d_in[14];
    const float* Wlin = (const float*)d_in[15];
    const float* blin = (const float*)d_in[16];

    float*    ws    = (float*)d_ws;
    unsigned* gcur  = (unsigned*)(ws + GCUR_O);
    float*    dis   = ws + DIS_O;
    int*      off   = (int*)(ws + OFF_O);
    u64*      cslot = (u64*)(ws + CSLOT_O);
    unsigned* rslot = (unsigned*)(ws + RSLOT_O);
    u64*      rw    = (u64*)(ws + RW_O);
    unsigned* abuf  = (unsigned*)(ws + ABUF_O);
    ushort_t* pbuf  = (ushort_t*)(ws + PBUF_O);
    unsigned* xs    = (unsigned*)(ws + XS_O);    // own region (no cslot alias)
    unsigned* t1s   = (unsigned*)(ws + T1S_O);   // aliases rslot (safe)

    hipMemsetAsync(d_ws, 0, 512 * 4, stream);    // just the cursors

    k1<<<NB1 + 1, 512, 0, stream>>>(ei, ew, Wxz, Wxh, gcur, cslot, rslot, pbuf);
    k2<<<NBKT * 2, 512, 0, stream>>>(x, gcur, cslot, rslot, dis, off, rw, abuf, xs);
    k_prop<<<12500, 256, 0, stream>>>(off, rw, xs, dis, x, abuf, t1s, 0);
    k_prop<<<12500, 256, 0, stream>>>(off, rw, t1s, dis, x, abuf, abuf, 1);
    k_gemm<<<782, 256, 0, stream>>>((const ushort_t*)abuf, pbuf, bxz, bhz, bxh, bhh,
                                    Wlin, blin, (float2*)d_out);
}

// Round 11
// 216.266 us; speedup vs baseline: 2.2121x; 1.0086x over previous
//
#include <hip/hip_runtime.h>
#include <hip/hip_bf16.h>

#define N_NODES 50000
#define N_EDGES 800000
#define NB1 400       // k1 bucketing blocks
#define CH  2000      // edges per k1 block (NB1*CH == N_EDGES)
#define NBKT 196      // MSD buckets = key>>8
#define CAP 8192      // slots per bucket (mean ~4082, +64 sigma headroom)
#define SORT_MAX 6144 // k2 LDS sort capacity per bucket (+32 sigma)

typedef unsigned short ushort_t;
typedef unsigned long long u64;
typedef __attribute__((ext_vector_type(8))) short bf16x8;
typedef __attribute__((ext_vector_type(4))) float f32x4;

// ---------------- workspace layout (4-byte word offsets) ----------------
constexpr int GCUR_O  = 0;           // uint[512]: [0,196) col cursors, [256,452) row cursors
constexpr int DIS_O   = 512;         // float[50000]
constexpr int OFF_O   = 50512;       // int[50001]
constexpr int CSLOT_O = 100544;      // u64[196*8192] col buckets (w | col8 | row16)
constexpr int RSLOT_O = 3311808;     // uint[196*8192] row buckets (w24 | row8); T1S after k2
constexpr int RW_O    = 4917440;     // u64[800000] CSR payload (w | row)
constexpr int ABUF_O  = 6517440;     // uint[50000*96] A=[x|tx1|tx2] bf16x2
constexpr int PBUF_O  = 11317440;    // ushort[24576] packed B
constexpr int XS_O    = 11329728;    // uint[50000*32] xs = dis*x (own region; must NOT alias cslot)
constexpr int T1S_O   = RSLOT_O;     // uint[50000*32] dis*tx1 (safe: rslot dead after k2)

__device__ __forceinline__ ushort_t f32_to_bf16(float f) {
    unsigned u = __float_as_uint(f);
    u += 0x7fffu + ((u >> 16) & 1u);   // round-to-nearest-even
    return (ushort_t)(u >> 16);
}
__device__ __forceinline__ float bflo(unsigned u) { return __uint_as_float(u << 16); }
__device__ __forceinline__ float bfhi(unsigned u) { return __uint_as_float(u & 0xffff0000u); }
__device__ __forceinline__ unsigned packbf2(float a, float b) {
    return (unsigned)f32_to_bf16(a) | ((unsigned)f32_to_bf16(b) << 16);
}
__device__ __forceinline__ float fsigmoid(float x) { return 1.f / (1.f + __expf(-x)); }
__device__ __forceinline__ float ftanh(float x) {
    x = fminf(15.f, fmaxf(-15.f, x));
    float e = __expf(2.f * x);
    return (e - 1.f) / (e + 1.f);
}

// inclusive shuffle-scan of 256 values held by threads t<256 (waves 0..3);
// 2 barriers instead of a 16-barrier ladder. Result valid for t<256.
__device__ __forceinline__ unsigned block_scan256_incl(unsigned v, int t, unsigned* wsum) {
    int lane = t & 63;
    unsigned sc = v;
#pragma unroll
    for (int o = 1; o < 64; o <<= 1) {
        unsigned u = __shfl_up(sc, o, 64);
        if (lane >= o) sc += u;
    }
    if (t < 256 && lane == 63) wsum[t >> 6] = sc;
    __syncthreads();
    if (t < 256) {
        int wid = t >> 6;
        unsigned off = 0;
#pragma unroll
        for (int wv = 0; wv < 3; ++wv) if (wv < wid) off += wsum[wv];
        sc += off;
    }
    __syncthreads();   // wsum free for reuse
    return sc;
}

// ---- k1: dual MSD bucketing (direct scatter — R8 version) + packB ----
__global__ __launch_bounds__(512) void k1(
    const int* __restrict__ ei, const float* __restrict__ ew,
    const float* __restrict__ Wxz, const float* __restrict__ Wxh,
    unsigned* __restrict__ gcur, u64* __restrict__ cslot,
    unsigned* __restrict__ rslot, ushort_t* __restrict__ pbuf) {
    int bid = blockIdx.x, t = threadIdx.x;
    if (bid < NB1) {
        __shared__ unsigned colbuf[CH], rowbuf[CH];
        __shared__ unsigned hc[256], hr[256], bc[256], br[256];
        if (t < 256) { hc[t] = 0; hr[t] = 0; }
        __syncthreads();
        int e0 = bid * CH;
        for (int i = t; i < CH; i += 512) {
            unsigned r = (unsigned)ei[e0 + i];
            unsigned c = (unsigned)ei[N_EDGES + e0 + i];
            rowbuf[i] = r;
            colbuf[i] = c;
            atomicAdd(&hc[c >> 8], 1u);
            atomicAdd(&hr[r >> 8], 1u);
        }
        __syncthreads();
        if (t < NBKT) {
            bc[t] = atomicAdd(&gcur[t], hc[t]);
            br[t] = atomicAdd(&gcur[256 + t], hr[t]);
        }
        __syncthreads();
        if (t < 256) { hc[t] = 0; hr[t] = 0; }   // reuse as local cursors
        __syncthreads();
        for (int i = t; i < CH; i += 512) {
            unsigned c = colbuf[i];
            unsigned r = rowbuf[i];
            unsigned w = __float_as_uint(ew[e0 + i]);
            unsigned dc = c >> 8;
            unsigned pc = bc[dc] + atomicAdd(&hc[dc], 1u);
            if (pc < CAP)
                cslot[(size_t)dc * CAP + pc] = ((u64)w << 32) | ((c & 255u) << 16) | (r & 0xFFFFu);
            unsigned dr = r >> 8;
            unsigned pr = br[dr] + atomicAdd(&hr[dr], 1u);
            if (pr < CAP) rslot[(size_t)dr * CAP + pr] = (w & 0xFFFFFF00u) | (r & 255u);
        }
    } else {                                     // pack B into MFMA fragment order
        for (int idx = t; idx < 24576; idx += 512) {
            int k = idx >> 7, n = idx & 127;
            float v = (n < 64) ? Wxz[k * 64 + n] : Wxh[k * 64 + (n - 64)];
            int c = n >> 4, s = k >> 5, l = (((k >> 3) & 3) << 4) | (n & 15), j = k & 7;
            pbuf[((c * 6 + s) * 64 + l) * 8 + j] = f32_to_bf16(v);
        }
    }
}

// ---- k2: blocks [0,196): per-bucket LDS sort -> off + direct-scatter rw
//          blocks [196,392): deg (LDS fadd) -> dis, x-cast + xs ----
__global__ __launch_bounds__(512) void k2(
    const float* __restrict__ x, const unsigned* __restrict__ gcur,
    const u64* __restrict__ cslot, const unsigned* __restrict__ rslot,
    float* __restrict__ dis, int* __restrict__ off, u64* __restrict__ rw,
    unsigned* __restrict__ abuf, unsigned* __restrict__ xs) {
    int bid = blockIdx.x, t = threadIdx.x;
    __shared__ unsigned rawA[SORT_MAX], rawB[SORT_MAX];
    __shared__ unsigned hist[256], hsc[256], cur[256], gs[256];
    __shared__ unsigned wsum[8];
    __shared__ float facc[256];

    if (bid < NBKT) {
        // ---- phase A: sort col bucket bid by col&255 -> off + (row,w) CSR ----
        unsigned szv = (t < NBKT) ? gcur[t] : 0u;            // t<256 holds size[t]
        unsigned inc = block_scan256_incl(szv, t, wsum);     // inclusive scan
        if (t < 256) gs[t] = inc - szv;                      // exclusive prefix
        if (t < 256) hist[t] = 0;
        __syncthreads();
        unsigned szb = gcur[bid];
        unsigned sz = min(szb, (unsigned)SORT_MAX);
        unsigned base = gs[bid];
        for (unsigned i = t; i < sz; i += 512) {
            u64 v = cslot[(size_t)bid * CAP + i];
            unsigned lo = (unsigned)v;
            rawA[i] = lo;
            rawB[i] = (unsigned)(v >> 32);
            atomicAdd(&hist[(lo >> 16) & 255u], 1u);
        }
        __syncthreads();
        unsigned h0 = (t < 256) ? hist[t] : 0u;
        unsigned hinc = block_scan256_incl(h0, t, wsum);
        if (t < 256) {
            hsc[t] = hinc - h0;                              // exclusive
            cur[t] = 0u;
            int c = bid * 256 + t;
            if (c <= N_NODES) off[c] = (int)(base + hsc[t]);
        }
        __syncthreads();
        for (unsigned i = t; i < sz; i += 512) {             // position + direct scatter
            unsigned lo = rawA[i];
            unsigned d = (lo >> 16) & 255u;
            unsigned p = hsc[d] + atomicAdd(&cur[d], 1u);
            rw[base + p] = ((u64)rawB[i] << 32) | (lo & 0xFFFFu);
        }
    } else {
        // ---- phase B: deg for rows [b*256,+256), dis, x-cast + xs ----
        int b = bid - NBKT;
        if (t < 256) facc[t] = 0.f;
        __syncthreads();
        unsigned szr = min(gcur[256 + b], (unsigned)CAP);
        const unsigned* rs = rslot + (size_t)b * CAP;
        for (unsigned i = t; i < szr; i += 512)
            atomicAdd(&facc[rs[i] & 255u], __uint_as_float(rs[i] & 0xFFFFFF00u));
        __syncthreads();
        if (t < 256) {
            float d = facc[t];
            float r = d > 0.f ? rsqrtf(d) : 0.f;
            facc[t] = r;
            int n = b * 256 + t;
            if (n < N_NODES) dis[n] = r;
        }
        __syncthreads();
        for (int idx = t; idx < 8192; idx += 512) {          // x-cast + xs from one x load
            int nl = idx >> 5, q = idx & 31;
            int n = b * 256 + nl;
            if (n < N_NODES) {
                float2 xv = ((const float2*)x)[n * 32 + q];
                float r = facc[nl];
                abuf[n * 96 + q] = packbf2(xv.x, xv.y);      // plain x bf16
                xs[n * 32 + q] = packbf2(r * xv.x, r * xv.y);// dis*x bf16
            }
        }
    }
}

// ---- prop: one wave per node; halves handle alternating edges (R8 config) ----
// mode 0: tx1 = -dis*sum(w*xs[row]); write abuf tx1 + t1s = dis*tx1
// mode 1: tx2 = 2*(-dis*sum(w*t1s[row])) - x(fp32); write abuf tx2
__global__ __launch_bounds__(256) void k_prop(
    const int* __restrict__ off, const u64* __restrict__ rw,
    const unsigned* __restrict__ xsrc, const float* __restrict__ dis,
    const float* __restrict__ xf, unsigned* __restrict__ abuf,
    unsigned* __restrict__ t1s, int mode) {
    int node = (blockIdx.x * 256 + threadIdx.x) >> 6;
    if (node >= N_NODES) return;
    int lane = threadIdx.x & 63, h = lane >> 5, q = lane & 31;
    int b = off[node], end = off[node + 1];
    float di = dis[node];
    float acc0 = 0.f, acc1 = 0.f;
    for (; b + 7 < end; b += 8) {
        u64 v0 = rw[b + h], v1 = rw[b + h + 2], v2 = rw[b + h + 4], v3 = rw[b + h + 6];
        unsigned u0 = xsrc[((unsigned)v0 & 0xFFFFu) * 32 + q];
        unsigned u1 = xsrc[((unsigned)v1 & 0xFFFFu) * 32 + q];
        unsigned u2 = xsrc[((unsigned)v2 & 0xFFFFu) * 32 + q];
        unsigned u3 = xsrc[((unsigned)v3 & 0xFFFFu) * 32 + q];
        float a0 = __uint_as_float((unsigned)(v0 >> 32));
        float a1 = __uint_as_float((unsigned)(v1 >> 32));
        float a2 = __uint_as_float((unsigned)(v2 >> 32));
        float a3 = __uint_as_float((unsigned)(v3 >> 32));
        acc0 += a0 * bflo(u0) + a1 * bflo(u1) + a2 * bflo(u2) + a3 * bflo(u3);
        acc1 += a0 * bfhi(u0) + a1 * bfhi(u1) + a2 * bfhi(u2) + a3 * bfhi(u3);
    }
    for (; b + 1 < end; b += 2) {
        u64 v = rw[b + h];
        unsigned u = xsrc[((unsigned)v & 0xFFFFu) * 32 + q];
        float a = __uint_as_float((unsigned)(v >> 32));
        acc0 += a * bflo(u); acc1 += a * bfhi(u);
    }
    if (b < end && h == 0) {
        u64 v = rw[b];
        unsigned u = xsrc[((unsigned)v & 0xFFFFu) * 32 + q];
        float a = __uint_as_float((unsigned)(v >> 32));
        acc0 += a * bflo(u); acc1 += a * bfhi(u);
    }
    acc0 += __shfl_xor(acc0, 32, 64);
    acc1 += __shfl_xor(acc1, 32, 64);
    if (h == 0) {
        float t0 = -di * acc0, t1v = -di * acc1;
        if (mode == 0) {
            abuf[node * 96 + 32 + q] = packbf2(t0, t1v);
            t1s[node * 32 + q] = packbf2(di * t0, di * t1v);
        } else {
            float2 xv = ((const float2*)xf)[node * 32 + q];
            abuf[node * 96 + 64 + q] = packbf2(2.f * t0 - xv.x, 2.f * t1v - xv.y);
        }
    }
}

// ---- MFMA GEMM [50048x192]@[192x128] + GRU combine + head ----
// 391 blocks x 2 node-tiles: halves redundant B traffic vs 782x1.
__global__ __launch_bounds__(256) void k_gemm(
    const ushort_t* __restrict__ ab, const ushort_t* __restrict__ pbuf,
    const float* __restrict__ bxz, const float* __restrict__ bhz,
    const float* __restrict__ bxh, const float* __restrict__ bhh,
    const float* __restrict__ Wlin, const float* __restrict__ blin,
    float2* __restrict__ out) {
    __shared__ ushort_t bsh[24576];
    int tid = threadIdx.x;
    {
        uint4* s4 = (uint4*)bsh;
        const uint4* g4 = (const uint4*)pbuf;
        for (int i = tid; i < 3072; i += 256) s4[i] = g4[i];
    }
    __syncthreads();

    int wave = tid >> 6, lane = tid & 63;
    int quad = lane >> 4, m = lane & 15;

    float bzv[4], bhv[4], wl0[4], wl1[4];
#pragma unroll
    for (int c = 0; c < 4; ++c) {
        int col = c * 16 + m;
        bzv[c] = bxz[col] + bhz[col];
        bhv[c] = bxh[col] + bhh[col];
        wl0[c] = Wlin[2 * col];
        wl1[c] = Wlin[2 * col + 1];
    }
    float bl0 = blin[0], bl1 = blin[1];

    for (int tile = 0; tile < 2; ++tile) {
        int n0 = (blockIdx.x * 2 + tile) * 64;
        int arow = n0 + wave * 16 + m;
        const ushort_t* ap = ab + (size_t)arow * 192 + quad * 8;

        f32x4 acc[8];
#pragma unroll
        for (int c = 0; c < 8; ++c) acc[c] = (f32x4){0.f, 0.f, 0.f, 0.f};
#pragma unroll
        for (int s = 0; s < 6; ++s) {
            bf16x8 af = *(const bf16x8*)(ap + s * 32);
#pragma unroll
            for (int c = 0; c < 8; ++c) {
                bf16x8 bfr = *(const bf16x8*)(bsh + ((c * 6 + s) * 64 + lane) * 8);
                acc[c] = __builtin_amdgcn_mfma_f32_16x16x32_bf16(af, bfr, acc[c], 0, 0, 0);
            }
        }
#pragma unroll
        for (int i = 0; i < 4; ++i) {
            float p0 = 0.f, p1 = 0.f;
#pragma unroll
            for (int c = 0; c < 4; ++c) {
                float z  = fsigmoid(acc[c][i] + bzv[c]);
                float ht = ftanh(acc[c + 4][i] + bhv[c]);
                float t  = ftanh((1.f - z) * ht);
                p0 += t * wl0[c];
                p1 += t * wl1[c];
            }
            for (int o = 1; o <= 8; o <<= 1) {
                p0 += __shfl_xor(p0, o, 64);
                p1 += __shfl_xor(p1, o, 64);
            }
            int g = n0 + wave * 16 + quad * 4 + i;
            if (m == 0 && g < N_NODES)
                out[g] = make_float2(fsigmoid(p0 + bl0), fsigmoid(p1 + bl1));
        }
    }
}

extern "C" void kernel_launch(void* const* d_in, const int* in_sizes, int n_in,
                              void* d_out, int out_size, void* d_ws, size_t ws_size,
                              hipStream_t stream) {
    const float* x    = (const float*)d_in[0];
    const int*   ei   = (const int*)d_in[1];
    const float* ew   = (const float*)d_in[2];
    const float* Wxz  = (const float*)d_in[3];
    const float* bxz  = (const float*)d_in[4];
    const float* bhz  = (const float*)d_in[6];
    const float* Wxh  = (const float*)d_in[11];
    const float* bxh  = (const float*)d_in[12];
    const float* bhh  = (const float*)d_in[14];
    const float* Wlin = (const float*)d_in[15];
    const float* blin = (const float*)d_in[16];

    float*    ws    = (float*)d_ws;
    unsigned* gcur  = (unsigned*)(ws + GCUR_O);
    float*    dis   = ws + DIS_O;
    int*      off   = (int*)(ws + OFF_O);
    u64*      cslot = (u64*)(ws + CSLOT_O);
    unsigned* rslot = (unsigned*)(ws + RSLOT_O);
    u64*      rw    = (u64*)(ws + RW_O);
    unsigned* abuf  = (unsigned*)(ws + ABUF_O);
    ushort_t* pbuf  = (ushort_t*)(ws + PBUF_O);
    unsigned* xs    = (unsigned*)(ws + XS_O);    // own region (no cslot alias)
    unsigned* t1s   = (unsigned*)(ws + T1S_O);   // aliases rslot (safe)

    hipMemsetAsync(d_ws, 0, 512 * 4, stream);    // just the cursors

    k1<<<NB1 + 1, 512, 0, stream>>>(ei, ew, Wxz, Wxh, gcur, cslot, rslot, pbuf);
    k2<<<NBKT * 2, 512, 0, stream>>>(x, gcur, cslot, rslot, dis, off, rw, abuf, xs);
    k_prop<<<12500, 256, 0, stream>>>(off, rw, xs, dis, x, abuf, t1s, 0);
    k_prop<<<12500, 256, 0, stream>>>(off, rw, t1s, dis, x, abuf, abuf, 1);
    k_gemm<<<391, 256, 0, stream>>>((const ushort_t*)abuf, pbuf, bxz, bhz, bxh, bhh,
                                    Wlin, blin, (float2*)d_out);
}

// Round 12
// 209.081 us; speedup vs baseline: 2.2881x; 1.0344x over previous
//
#include <hip/hip_runtime.h>
#include <hip/hip_bf16.h>

#define N_NODES 50000
#define N_EDGES 800000
#define NB1 400       // k1 bucketing blocks
#define CH  2000      // edges per k1 block (NB1*CH == N_EDGES)
#define NBKT 196      // MSD buckets = key>>8
#define CAP 8192      // slots per bucket (mean ~4082, +64 sigma headroom)
#define SORT_MAX 6144 // k2 LDS sort capacity per bucket (+32 sigma)

typedef unsigned short ushort_t;
typedef unsigned long long u64;
typedef __attribute__((ext_vector_type(8))) short bf16x8;
typedef __attribute__((ext_vector_type(4))) float f32x4;

// ---------------- workspace layout (4-byte word offsets) ----------------
constexpr int GCUR_O  = 0;           // uint[512]: [0,196) col cursors, [256,452) row cursors
constexpr int DIS_O   = 512;         // float[50000]
constexpr int OFF_O   = 50512;       // int[50001]
constexpr int CSLOT_O = 100544;      // u64[196*8192] col buckets (w | dc8 | col8 | row16)
constexpr int RSLOT_O = 3311808;     // uint[196*8192] row buckets (w24 | row8); T1S after k2
constexpr int RW_O    = 4917440;     // u64[800000] CSR payload (w | row)
constexpr int ABUF_O  = 6517440;     // uint[50000*96] A=[x|tx1|tx2] bf16x2
constexpr int PBUF_O  = 11317440;    // ushort[24576] packed B
constexpr int XS_O    = 11329728;    // uint[50000*32] xs = dis*x (own region; must NOT alias cslot)
constexpr int T1S_O   = RSLOT_O;     // uint[50000*32] dis*tx1 (safe: rslot dead after k2)

__device__ __forceinline__ ushort_t f32_to_bf16(float f) {
    unsigned u = __float_as_uint(f);
    u += 0x7fffu + ((u >> 16) & 1u);   // round-to-nearest-even
    return (ushort_t)(u >> 16);
}
__device__ __forceinline__ float bflo(unsigned u) { return __uint_as_float(u << 16); }
__device__ __forceinline__ float bfhi(unsigned u) { return __uint_as_float(u & 0xffff0000u); }
__device__ __forceinline__ unsigned packbf2(float a, float b) {
    return (unsigned)f32_to_bf16(a) | ((unsigned)f32_to_bf16(b) << 16);
}
__device__ __forceinline__ float fsigmoid(float x) { return 1.f / (1.f + __expf(-x)); }
__device__ __forceinline__ float ftanh(float x) {
    x = fminf(15.f, fmaxf(-15.f, x));
    float e = __expf(2.f * x);
    return (e - 1.f) / (e + 1.f);
}

// inclusive shuffle-scan of 256 values held by threads t<256 (waves 0..3);
// 2 barriers instead of a 16-barrier ladder. Result valid for t<256.
__device__ __forceinline__ unsigned block_scan256_incl(unsigned v, int t, unsigned* wsum) {
    int lane = t & 63;
    unsigned sc = v;
#pragma unroll
    for (int o = 1; o < 64; o <<= 1) {
        unsigned u = __shfl_up(sc, o, 64);
        if (lane >= o) sc += u;
    }
    if (t < 256 && lane == 63) wsum[t >> 6] = sc;
    __syncthreads();
    if (t < 256) {
        int wid = t >> 6;
        unsigned off = 0;
#pragma unroll
        for (int wv = 0; wv < 3; ++wv) if (wv < wid) off += wsum[wv];
        sc += off;
    }
    __syncthreads();   // wsum free for reuse
    return sc;
}

// ---- k1: dual MSD bucketing with LDS ORDER MAP -> run-coalesced bucket writes ----
// R8's direct scatter: ~64 scattered 8B stores per wave (64 L2 tx). Here we stage
// payloads once, build u16 order maps, and emit bucket-sorted runs (mean ~10)
// -> ~7-13 L2 tx per wave. Only 34 KB LDS (R10's version used 50 KB + 2 copies).
__global__ __launch_bounds__(512) void k1(
    const int* __restrict__ ei, const float* __restrict__ ew,
    const float* __restrict__ Wxz, const float* __restrict__ Wxh,
    unsigned* __restrict__ gcur, u64* __restrict__ cslot,
    unsigned* __restrict__ rslot, ushort_t* __restrict__ pbuf) {
    int bid = blockIdx.x, t = threadIdx.x;
    __shared__ u64 pC[CH];                       // 16 KB payloads in load order
    __shared__ ushort_t ordC[CH], ordR[CH];      // 8 KB sorted_pos -> load idx
    __shared__ unsigned char digC[CH], digR[CH]; // 4 KB digit at sorted pos
    __shared__ unsigned hc[256], hr[256], scC[256], scR[256], bc[256], br[256];
    __shared__ unsigned wsum[8];
    if (bid < NB1) {
        if (t < 256) { hc[t] = 0; hr[t] = 0; }
        __syncthreads();
        int e0 = bid * CH;
        for (int i = t; i < CH; i += 512) {      // pass 1: stage + histograms
            unsigned r = (unsigned)ei[e0 + i];
            unsigned c = (unsigned)ei[N_EDGES + e0 + i];
            unsigned w = __float_as_uint(ew[e0 + i]);
            unsigned dc = c >> 8;
            pC[i] = ((u64)w << 32) | (dc << 24) | ((c & 255u) << 16) | (r & 0xFFFFu);
            atomicAdd(&hc[dc], 1u);
            atomicAdd(&hr[r >> 8], 1u);
        }
        __syncthreads();
        if (t < NBKT) {                          // global slot allocation
            bc[t] = atomicAdd(&gcur[t], hc[t]);
            br[t] = atomicAdd(&gcur[256 + t], hr[t]);
        }
        unsigned vC = (t < 256) ? hc[t] : 0u;
        unsigned vR = (t < 256) ? hr[t] : 0u;
        unsigned iC = block_scan256_incl(vC, t, wsum);
        unsigned iR = block_scan256_incl(vR, t, wsum);
        if (t < 256) {
            scC[t] = iC - vC;                    // exclusive prefixes
            scR[t] = iR - vR;
            hc[t] = 0; hr[t] = 0;                // reuse as local cursors
        }
        __syncthreads();
        for (int i = t; i < CH; i += 512) {      // pass 2: build order maps
            u64 p = pC[i];
            unsigned dc = (unsigned)(p >> 24) & 255u;
            unsigned pc = scC[dc] + atomicAdd(&hc[dc], 1u);
            ordC[pc] = (ushort_t)i;
            digC[pc] = (unsigned char)dc;
            unsigned r = (unsigned)p & 0xFFFFu;
            unsigned dr = r >> 8;
            unsigned pr = scR[dr] + atomicAdd(&hr[dr], 1u);
            ordR[pr] = (ushort_t)i;
            digR[pr] = (unsigned char)dr;
        }
        __syncthreads();
        for (int i = t; i < CH; i += 512) {      // pass 3: run-coalesced emission
            unsigned dc = digC[i];
            u64 p = pC[ordC[i]];
            unsigned slotC = bc[dc] + (unsigned)i - scC[dc];
            if (slotC < CAP) cslot[(size_t)dc * CAP + slotC] = p;
            unsigned dr = digR[i];
            u64 q = pC[ordR[i]];
            unsigned slotR = br[dr] + (unsigned)i - scR[dr];
            if (slotR < CAP)
                rslot[(size_t)dr * CAP + slotR] =
                    ((unsigned)(q >> 32) & 0xFFFFFF00u) | ((unsigned)q & 255u);
        }
    } else {                                     // pack B into MFMA fragment order
        for (int idx = t; idx < 24576; idx += 512) {
            int k = idx >> 7, n = idx & 127;
            float v = (n < 64) ? Wxz[k * 64 + n] : Wxh[k * 64 + (n - 64)];
            int c = n >> 4, s = k >> 5, l = (((k >> 3) & 3) << 4) | (n & 15), j = k & 7;
            pbuf[((c * 6 + s) * 64 + l) * 8 + j] = f32_to_bf16(v);
        }
    }
}

// ---- k2: blocks [0,196): per-bucket sort -> off + COALESCED rw stream-out
//          blocks [196,392): deg (LDS fadd) -> dis, x-cast + xs ----
__global__ __launch_bounds__(512) void k2(
    const float* __restrict__ x, const unsigned* __restrict__ gcur,
    const u64* __restrict__ cslot, const unsigned* __restrict__ rslot,
    float* __restrict__ dis, int* __restrict__ off, u64* __restrict__ rw,
    unsigned* __restrict__ abuf, unsigned* __restrict__ xs) {
    int bid = blockIdx.x, t = threadIdx.x;
    __shared__ u64 srt[SORT_MAX];                // 48 KB bucket-sorted payloads
    __shared__ unsigned hist[256], hsc[256], cur[256], gs[256];
    __shared__ unsigned wsum[8];
    __shared__ float facc[256];

    if (bid < NBKT) {
        // ---- phase A: sort col bucket bid by col&255 -> off + coalesced rw ----
        unsigned szv = (t < NBKT) ? gcur[t] : 0u;
        unsigned inc = block_scan256_incl(szv, t, wsum);
        if (t < 256) gs[t] = inc - szv;          // exclusive prefix of bucket sizes
        if (t < 256) hist[t] = 0;
        __syncthreads();
        unsigned szb = gcur[bid];
        unsigned sz = min(szb, (unsigned)SORT_MAX);
        unsigned base = gs[bid];
        const u64* cs = cslot + (size_t)bid * CAP;
        for (unsigned i = t; i < sz; i += 512)   // read 1 (coalesced): digit hist
            atomicAdd(&hist[((unsigned)cs[i] >> 16) & 255u], 1u);
        __syncthreads();
        unsigned h0 = (t < 256) ? hist[t] : 0u;
        unsigned hinc = block_scan256_incl(h0, t, wsum);
        if (t < 256) {
            hsc[t] = hinc - h0;                  // exclusive
            cur[t] = 0u;
            int c = bid * 256 + t;
            if (c <= N_NODES) off[c] = (int)(base + hsc[t]);
        }
        __syncthreads();
        for (unsigned i = t; i < sz; i += 512) { // read 2 (L2-hot): LDS scatter
            u64 v = cs[i];
            unsigned d = ((unsigned)v >> 16) & 255u;
            unsigned p = hsc[d] + atomicAdd(&cur[d], 1u);
            srt[p] = v;
        }
        __syncthreads();
        for (unsigned i = t; i < sz; i += 512) { // coalesced rw stream-out
            u64 v = srt[i];
            rw[base + i] = ((v >> 32) << 32) | ((unsigned)v & 0xFFFFu);
        }
    } else {
        // ---- phase B: deg for rows [b*256,+256), dis, x-cast + xs ----
        int b = bid - NBKT;
        if (t < 256) facc[t] = 0.f;
        __syncthreads();
        unsigned szr = min(gcur[256 + b], (unsigned)CAP);
        const unsigned* rs = rslot + (size_t)b * CAP;
        for (unsigned i = t; i < szr; i += 512)
            atomicAdd(&facc[rs[i] & 255u], __uint_as_float(rs[i] & 0xFFFFFF00u));
        __syncthreads();
        if (t < 256) {
            float d = facc[t];
            float r = d > 0.f ? rsqrtf(d) : 0.f;
            facc[t] = r;
            int n = b * 256 + t;
            if (n < N_NODES) dis[n] = r;
        }
        __syncthreads();
        for (int idx = t; idx < 8192; idx += 512) {   // x-cast + xs from one x load
            int nl = idx >> 5, q = idx & 31;
            int n = b * 256 + nl;
            if (n < N_NODES) {
                float2 xv = ((const float2*)x)[n * 32 + q];
                float r = facc[nl];
                abuf[n * 96 + q] = packbf2(xv.x, xv.y);       // plain x bf16
                xs[n * 32 + q] = packbf2(r * xv.x, r * xv.y); // dis*x bf16
            }
        }
    }
}

// ---- prop: one wave per node; halves handle alternating edges ----
// mode 0: tx1 = -dis*sum(w*xs[row]); write abuf tx1 + t1s = dis*tx1
// mode 1: tx2 = 2*(-dis*sum(w*t1s[row])) - x(fp32); write abuf tx2
__global__ __launch_bounds__(256) void k_prop(
    const int* __restrict__ off, const u64* __restrict__ rw,
    const unsigned* __restrict__ xsrc, const float* __restrict__ dis,
    const float* __restrict__ xf, unsigned* __restrict__ abuf,
    unsigned* __restrict__ t1s, int mode) {
    int node = (blockIdx.x * 256 + threadIdx.x) >> 6;
    if (node >= N_NODES) return;
    int lane = threadIdx.x & 63, h = lane >> 5, q = lane & 31;
    int b = off[node], end = off[node + 1];
    float di = dis[node];
    float acc0 = 0.f, acc1 = 0.f;
    for (; b + 7 < end; b += 8) {
        u64 v0 = rw[b + h], v1 = rw[b + h + 2], v2 = rw[b + h + 4], v3 = rw[b + h + 6];
        unsigned u0 = xsrc[((unsigned)v0 & 0xFFFFu) * 32 + q];
        unsigned u1 = xsrc[((unsigned)v1 & 0xFFFFu) * 32 + q];
        unsigned u2 = xsrc[((unsigned)v2 & 0xFFFFu) * 32 + q];
        unsigned u3 = xsrc[((unsigned)v3 & 0xFFFFu) * 32 + q];
        float a0 = __uint_as_float((unsigned)(v0 >> 32));
        float a1 = __uint_as_float((unsigned)(v1 >> 32));
        float a2 = __uint_as_float((unsigned)(v2 >> 32));
        float a3 = __uint_as_float((unsigned)(v3 >> 32));
        acc0 += a0 * bflo(u0) + a1 * bflo(u1) + a2 * bflo(u2) + a3 * bflo(u3);
        acc1 += a0 * bfhi(u0) + a1 * bfhi(u1) + a2 * bfhi(u2) + a3 * bfhi(u3);
    }
    for (; b + 1 < end; b += 2) {
        u64 v = rw[b + h];
        unsigned u = xsrc[((unsigned)v & 0xFFFFu) * 32 + q];
        float a = __uint_as_float((unsigned)(v >> 32));
        acc0 += a * bflo(u); acc1 += a * bfhi(u);
    }
    if (b < end && h == 0) {
        u64 v = rw[b];
        unsigned u = xsrc[((unsigned)v & 0xFFFFu) * 32 + q];
        float a = __uint_as_float((unsigned)(v >> 32));
        acc0 += a * bflo(u); acc1 += a * bfhi(u);
    }
    acc0 += __shfl_xor(acc0, 32, 64);
    acc1 += __shfl_xor(acc1, 32, 64);
    if (h == 0) {
        float t0 = -di * acc0, t1v = -di * acc1;
        if (mode == 0) {
            abuf[node * 96 + 32 + q] = packbf2(t0, t1v);
            t1s[node * 32 + q] = packbf2(di * t0, di * t1v);
        } else {
            float2 xv = ((const float2*)xf)[node * 32 + q];
            abuf[node * 96 + 64 + q] = packbf2(2.f * t0 - xv.x, 2.f * t1v - xv.y);
        }
    }
}

// ---- MFMA GEMM [50048x192]@[192x128] + GRU combine + head (2 tiles/block) ----
__global__ __launch_bounds__(256) void k_gemm(
    const ushort_t* __restrict__ ab, const ushort_t* __restrict__ pbuf,
    const float* __restrict__ bxz, const float* __restrict__ bhz,
    const float* __restrict__ bxh, const float* __restrict__ bhh,
    const float* __restrict__ Wlin, const float* __restrict__ blin,
    float2* __restrict__ out) {
    __shared__ ushort_t bsh[24576];
    int tid = threadIdx.x;
    {
        uint4* s4 = (uint4*)bsh;
        const uint4* g4 = (const uint4*)pbuf;
        for (int i = tid; i < 3072; i += 256) s4[i] = g4[i];
    }
    __syncthreads();

    int wave = tid >> 6, lane = tid & 63;
    int quad = lane >> 4, m = lane & 15;

    float bzv[4], bhv[4], wl0[4], wl1[4];
#pragma unroll
    for (int c = 0; c < 4; ++c) {
        int col = c * 16 + m;
        bzv[c] = bxz[col] + bhz[col];
        bhv[c] = bxh[col] + bhh[col];
        wl0[c] = Wlin[2 * col];
        wl1[c] = Wlin[2 * col + 1];
    }
    float bl0 = blin[0], bl1 = blin[1];

    for (int tile = 0; tile < 2; ++tile) {
        int n0 = (blockIdx.x * 2 + tile) * 64;
        int arow = n0 + wave * 16 + m;
        const ushort_t* ap = ab + (size_t)arow * 192 + quad * 8;

        f32x4 acc[8];
#pragma unroll
        for (int c = 0; c < 8; ++c) acc[c] = (f32x4){0.f, 0.f, 0.f, 0.f};
#pragma unroll
        for (int s = 0; s < 6; ++s) {
            bf16x8 af = *(const bf16x8*)(ap + s * 32);
#pragma unroll
            for (int c = 0; c < 8; ++c) {
                bf16x8 bfr = *(const bf16x8*)(bsh + ((c * 6 + s) * 64 + lane) * 8);
                acc[c] = __builtin_amdgcn_mfma_f32_16x16x32_bf16(af, bfr, acc[c], 0, 0, 0);
            }
        }
#pragma unroll
        for (int i = 0; i < 4; ++i) {
            float p0 = 0.f, p1 = 0.f;
#pragma unroll
            for (int c = 0; c < 4; ++c) {
                float z  = fsigmoid(acc[c][i] + bzv[c]);
                float ht = ftanh(acc[c + 4][i] + bhv[c]);
                float t  = ftanh((1.f - z) * ht);
                p0 += t * wl0[c];
                p1 += t * wl1[c];
            }
            for (int o = 1; o <= 8; o <<= 1) {
                p0 += __shfl_xor(p0, o, 64);
                p1 += __shfl_xor(p1, o, 64);
            }
            int g = n0 + wave * 16 + quad * 4 + i;
            if (m == 0 && g < N_NODES)
                out[g] = make_float2(fsigmoid(p0 + bl0), fsigmoid(p1 + bl1));
        }
    }
}

extern "C" void kernel_launch(void* const* d_in, const int* in_sizes, int n_in,
                              void* d_out, int out_size, void* d_ws, size_t ws_size,
                              hipStream_t stream) {
    const float* x    = (const float*)d_in[0];
    const int*   ei   = (const int*)d_in[1];
    const float* ew   = (const float*)d_in[2];
    const float* Wxz  = (const float*)d_in[3];
    const float* bxz  = (const float*)d_in[4];
    const float* bhz  = (const float*)d_in[6];
    const float* Wxh  = (const float*)d_in[11];
    const float* bxh  = (const float*)d_in[12];
    const float* bhh  = (const float*)d_in[14];
    const float* Wlin = (const float*)d_in[15];
    const float* blin = (const float*)d_in[16];

    float*    ws    = (float*)d_ws;
    unsigned* gcur  = (unsigned*)(ws + GCUR_O);
    float*    dis   = ws + DIS_O;
    int*      off   = (int*)(ws + OFF_O);
    u64*      cslot = (u64*)(ws + CSLOT_O);
    unsigned* rslot = (unsigned*)(ws + RSLOT_O);
    u64*      rw    = (u64*)(ws + RW_O);
    unsigned* abuf  = (unsigned*)(ws + ABUF_O);
    ushort_t* pbuf  = (ushort_t*)(ws + PBUF_O);
    unsigned* xs    = (unsigned*)(ws + XS_O);    // own region (no cslot alias)
    unsigned* t1s   = (unsigned*)(ws + T1S_O);   // aliases rslot (safe)

    hipMemsetAsync(d_ws, 0, 512 * 4, stream);    // just the cursors

    k1<<<NB1 + 1, 512, 0, stream>>>(ei, ew, Wxz, Wxh, gcur, cslot, rslot, pbuf);
    k2<<<NBKT * 2, 512, 0, stream>>>(x, gcur, cslot, rslot, dis, off, rw, abuf, xs);
    k_prop<<<12500, 256, 0, stream>>>(off, rw, xs, dis, x, abuf, t1s, 0);
    k_prop<<<12500, 256, 0, stream>>>(off, rw, t1s, dis, x, abuf, abuf, 1);
    k_gemm<<<391, 256, 0, stream>>>((const ushort_t*)abuf, pbuf, bxz, bhz, bxh, bhh,
                                    Wlin, blin, (float2*)d_out);
}